// Round 3
// baseline (556.346 us; speedup 1.0000x reference)
//
#include <hip/hip_runtime.h>

#define HO 62
#define WO 62
#define CIN 32
#define COUT 64
#define BATCH 16
#define KROW 288              // CIN*9 floats per (position, o) weight row
#define NJT 31                // j-tiles of 2 columns each
#define NXCD 8

// weight rows are 1152 B (16B-aligned); x loads are 8B-aligned (j0 even)
typedef float f4w __attribute__((ext_vector_type(4), aligned(16)));
typedef float f4x __attribute__((ext_vector_type(4), aligned(8)));

// static component pick from an f4w[9] chunk (compile-time idx -> stays in VGPRs)
#define WSEL(arr, idx) (arr[(idx) >> 2][(idx) & 3])

__global__ __launch_bounds__(64, 2)
void lc2d_kernel(const float* __restrict__ x,
                 const float* __restrict__ wgt,
                 float* __restrict__ out) {
    // bijective XCD chunk swizzle (nwg=1922, q=240, r=2; m204 formula).
    // j-tile fastest within a chunk -> sequential weight streaming per XCD,
    // same-i x slab stays hot in that XCD's L2.
    const int orig = blockIdx.x;
    const int nwg  = HO * NJT;
    const int qch  = nwg / NXCD, rch = nwg % NXCD;
    const int xcd  = orig % NXCD, cpos = orig / NXCD;
    const int wg   = ((xcd < rch) ? xcd * (qch + 1)
                                  : rch * (qch + 1) + (xcd - rch) * qch) + cpos;
    const int i  = wg / NJT;
    const int j0 = (wg % NJT) * 2;          // 0,2,...,60
    const int pj = i * WO + j0;

    const int o = threadIdx.x;              // lane = output channel (one wave/block)

    // this thread's two private weight rows: used by NO other thread -> no LDS,
    // no barriers; streamed global->register once.
    const float* w0 = wgt + ((size_t)pj * COUT + o) * KROW;
    const float* w1 = w0 + (size_t)COUT * KROW;      // position pj+1

    // uniform per-batch x plane bases (SGPR pairs; loads become saddr+voffset)
    const float* xb[BATCH];
    #pragma unroll
    for (int b = 0; b < BATCH; ++b) xb[b] = x + (size_t)b * (CIN * 64 * 64);

    float a0[BATCH], a1[BATCH];
    #pragma unroll
    for (int b = 0; b < BATCH; ++b) { a0[b] = 0.0f; a1[b] = 0.0f; }

    for (int ch = 0; ch < 8; ++ch) {        // 4 input channels per chunk
        // 18 independent 16B loads: the HBM stream, ~9KB/wave in flight
        f4w wa[9], wb[9];
        #pragma unroll
        for (int q = 0; q < 9; ++q) {
            wa[q] = *(const f4w*)(w0 + ch * 36 + q * 4);
            wb[q] = *(const f4w*)(w1 + ch * 36 + q * 4);
        }
        #pragma unroll
        for (int cc = 0; cc < 4; ++cc) {
            #pragma unroll
            for (int kh = 0; kh < 3; ++kh) {
                const int off = (((ch * 4 + cc) * 64) + i + kh) * 64 + j0;
                const int kb  = cc * 9 + kh * 3;
                #pragma unroll
                for (int b = 0; b < BATCH; ++b) {
                    // wave-uniform float4: cols j0..j0+3 cover both j windows
                    const f4x xv = *(const f4x*)(xb[b] + off);
                    a0[b] += WSEL(wa, kb + 0) * xv.x;
                    a0[b] += WSEL(wa, kb + 1) * xv.y;
                    a0[b] += WSEL(wa, kb + 2) * xv.z;
                    a1[b] += WSEL(wb, kb + 0) * xv.y;
                    a1[b] += WSEL(wb, kb + 1) * xv.z;
                    a1[b] += WSEL(wb, kb + 2) * xv.w;
                }
            }
        }
    }

    // epilogue: sigmoid + float2 store along j (pj even -> 8B aligned)
    #pragma unroll
    for (int b = 0; b < BATCH; ++b) {
        float* op = out + (size_t)(b * COUT + o) * (HO * WO) + pj;
        float2 s;
        s.x = 1.0f / (1.0f + __expf(-a0[b]));
        s.y = 1.0f / (1.0f + __expf(-a1[b]));
        *(float2*)op = s;
    }
}

extern "C" void kernel_launch(void* const* d_in, const int* in_sizes, int n_in,
                              void* d_out, int out_size, void* d_ws, size_t ws_size,
                              hipStream_t stream) {
    const float* x   = (const float*)d_in[0];
    const float* wgt = (const float*)d_in[1];
    float* out       = (float*)d_out;
    const int grid = HO * NJT;              // 1922 single-wave blocks
    lc2d_kernel<<<dim3(grid), dim3(64), 0, stream>>>(x, wgt, out);
}